// Round 1
// baseline (1337.063 us; speedup 1.0000x reference)
//
#include <hip/hip_runtime.h>

// ---------------------------------------------------------------------------
// LiBNet forward: binarized CNN, B=512
//  conv1(3->64,4x4,pad(1,2,1,2)) -> shiftBN -> maxpool2
//  -> sign -> gconv(64,g=32,4x4,pad) -> shiftBN -> sign -> 1x1(64->256) -> shiftBN -> maxpool2
//  -> sign -> gconv(256,g=128,4x4,pad) -> shiftBN -> sign -> 1x1(256->256) -> shiftBN
//  -> FC(16384->10)
// ---------------------------------------------------------------------------

static __device__ __forceinline__ float fsign(float x) {
    return (x > 0.f) ? 1.f : ((x < 0.f) ? -1.f : 0.f);
}
static __device__ __forceinline__ int isign(float x) {
    return (x > 0.f) ? 1 : ((x < 0.f) ? -1 : 0);
}

// --- conv1: real input [512,3,32,32], binarized 4x4 weights, pad(1,2,1,2) ---
__global__ __launch_bounds__(256) void k_conv1(const float* __restrict__ x,
                                               const float* __restrict__ w1,
                                               float* __restrict__ out)
{
    __shared__ float sw[64 * 48];
    for (int i = threadIdx.x; i < 64 * 48; i += 256) sw[i] = fsign(w1[i]);
    __syncthreads();
    int t = blockIdx.x * 256 + threadIdx.x;
    int w = t & 31, h = (t >> 5) & 31, oc = (t >> 10) & 63, b = t >> 16;
    const float* xb = x + (size_t)b * 3 * 1024;
    const float* wp = sw + oc * 48;
    float acc = 0.f;
#pragma unroll
    for (int ic = 0; ic < 3; ++ic) {
        const float* xc = xb + ic * 1024;
#pragma unroll
        for (int kh = 0; kh < 4; ++kh) {
            int ih = h - 1 + kh;
            if ((unsigned)ih < 32u) {
                const float* xr = xc + ih * 32;
#pragma unroll
                for (int kw = 0; kw < 4; ++kw) {
                    int iw = w - 1 + kw;
                    if ((unsigned)iw < 32u)
                        acc += xr[iw] * wp[ic * 16 + kh * 4 + kw];
                }
            }
        }
    }
    out[t] = acc;
}

// --- per-channel sum/sumsq partials (deterministic, double precision) ---
__global__ __launch_bounds__(256) void k_stats(const float* __restrict__ in,
                                               double* __restrict__ part,
                                               int C, int HW, int bPerChunk)
{
    int c = blockIdx.x;
    int chunk = blockIdx.y;
    int b0 = chunk * bPerChunk;
    double s = 0.0, sq = 0.0;
    for (int b = b0; b < b0 + bPerChunk; ++b) {
        const float* p = in + (size_t)(b * C + c) * HW;
        for (int i = threadIdx.x; i < HW; i += 256) {
            double v = (double)p[i];
            s += v; sq += v * v;
        }
    }
    __shared__ double ss[256];
    __shared__ double sb[256];
    ss[threadIdx.x] = s; sb[threadIdx.x] = sq;
    __syncthreads();
    for (int st = 128; st > 0; st >>= 1) {
        if (threadIdx.x < st) {
            ss[threadIdx.x] += ss[threadIdx.x + st];
            sb[threadIdx.x] += sb[threadIdx.x + st];
        }
        __syncthreads();
    }
    if (threadIdx.x == 0) {
        int nch = gridDim.y;
        part[(size_t)(c * nch + chunk) * 2]     = ss[0];
        part[(size_t)(c * nch + chunk) * 2 + 1] = sb[0];
    }
}

// --- finalize: mean/var -> power-of-two shift scale; st = {mean,scale,beta} ---
__global__ void k_finalize(const double* __restrict__ part, int nch, int N,
                           const float* __restrict__ gamma,
                           const float* __restrict__ beta,
                           float4* __restrict__ st, int C)
{
    int c = blockIdx.x * blockDim.x + threadIdx.x;
    if (c >= C) return;
    double s = 0.0, sq = 0.0;
    for (int i = 0; i < nch; ++i) {
        s  += part[(size_t)(c * nch + i) * 2];
        sq += part[(size_t)(c * nch + i) * 2 + 1];
    }
    double mean = s / (double)N;
    double var = sq / (double)N - mean * mean;
    float inv = gamma[c] / sqrtf((float)var + 1e-5f);
    float sh = rintf(log2f(fabsf(inv) + 1e-12f));
    sh = fminf(fmaxf(sh, -4.f), 4.f);
    float scale = copysignf(exp2f(sh), inv);
    st[c] = make_float4((float)mean, scale, beta[c], 0.f);
}

// --- bn apply + 2x2 maxpool ---
template <int C, int H>
__global__ __launch_bounds__(256) void k_bnpool(const float* __restrict__ in,
                                                const float4* __restrict__ st,
                                                float* __restrict__ out)
{
    constexpr int Ho = H / 2;
    int t = blockIdx.x * 256 + threadIdx.x;
    int ow = t % Ho; int r = t / Ho;
    int oh = r % Ho; r /= Ho;
    int c = r % C; int b = r / C;
    float4 s = st[c];
    const float* p = in + ((size_t)((b * C + c) * H + oh * 2)) * H + ow * 2;
    float v0 = (p[0]     - s.x) * s.y + s.z;
    float v1 = (p[1]     - s.x) * s.y + s.z;
    float v2 = (p[H]     - s.x) * s.y + s.z;
    float v3 = (p[H + 1] - s.x) * s.y + s.z;
    out[t] = fmaxf(fmaxf(v0, v1), fmaxf(v2, v3));
}

// --- grouped 4x4 binary conv (in_per_group=2, out_per_group=2), pad(1,2,1,2) ---
// input: real f32 (binarized on the fly; pad zeros contribute 0)
template <int C, int H>
__global__ __launch_bounds__(256) void k_convg(const float* __restrict__ in,
                                               const float* __restrict__ wg,
                                               float* __restrict__ out)
{
    __shared__ signed char sw[C * 32];
    for (int i = threadIdx.x; i < C * 32; i += 256) sw[i] = (signed char)isign(wg[i]);
    __syncthreads();
    int t = blockIdx.x * 256 + threadIdx.x;
    int w = t % H; int r = t / H;
    int h = r % H; r /= H;
    int oc = r % C; int b = r / C;
    int g = oc >> 1;
    const float* p0 = in + (size_t)(b * C + 2 * g) * H * H;
    const signed char* wp = sw + oc * 32;
    int acc = 0;
#pragma unroll
    for (int j = 0; j < 2; ++j) {
        const float* pc = p0 + j * H * H;
#pragma unroll
        for (int kh = 0; kh < 4; ++kh) {
            int ih = h - 1 + kh;
            if ((unsigned)ih < (unsigned)H) {
#pragma unroll
                for (int kw = 0; kw < 4; ++kw) {
                    int iw = w - 1 + kw;
                    if ((unsigned)iw < (unsigned)H)
                        acc += isign(pc[ih * H + iw]) * (int)wp[j * 16 + kh * 4 + kw];
                }
            }
        }
    }
    out[t] = (float)acc;
}

// --- bn apply + binarize -> int8 ---
template <int C, int HW>
__global__ __launch_bounds__(256) void k_bnbin(const float* __restrict__ in,
                                               const float4* __restrict__ st,
                                               signed char* __restrict__ out)
{
    int t = blockIdx.x * 256 + threadIdx.x;
    int c = (t / HW) % C;
    float4 s = st[c];
    float v = (in[t] - s.x) * s.y + s.z;
    out[t] = (signed char)isign(v);
}

// --- weight sign -> int8 ---
__global__ void k_wsign(const float* __restrict__ w, signed char* __restrict__ out, int n)
{
    int t = blockIdx.x * blockDim.x + threadIdx.x;
    if (t < n) out[t] = (signed char)isign(w[t]);
}

// --- 1x1 binary conv (integer GEMM). Each thread: 4 spatial positions. ---
template <int Cin, int Cout, int HW>
__global__ __launch_bounds__(256) void k_conv1x1(const signed char* __restrict__ s_in,
                                                 const signed char* __restrict__ s_w,
                                                 float* __restrict__ out)
{
    constexpr int HW4 = HW / 4;
    int t = blockIdx.x * 256 + threadIdx.x;
    int hw4 = t % HW4; int r = t / HW4;
    int oc = r % Cout; int b = r / Cout;
    const int* ip = (const int*)s_in + (size_t)b * Cin * HW4 + hw4;
    const signed char* wp = s_w + oc * Cin;
    int a0 = 0, a1 = 0, a2 = 0, a3 = 0;
#pragma unroll 4
    for (int ic = 0; ic < Cin; ++ic) {
        int v = ip[ic * HW4];
        int wv = (int)wp[ic];
        a0 += ((v << 24) >> 24) * wv;
        a1 += ((v << 16) >> 24) * wv;
        a2 += ((v << 8)  >> 24) * wv;
        a3 += (v >> 24) * wv;
    }
    float4 o = make_float4((float)a0, (float)a1, (float)a2, (float)a3);
    ((float4*)out)[t] = o;
}

// --- FC with bn3_2 fused: out[b,n] = sum_k bn(f[b,k]) * fcw[n,k] + fcb[n] ---
__global__ __launch_bounds__(64) void k_fc(const float* __restrict__ f,
                                           const float4* __restrict__ st,
                                           const float* __restrict__ fcw,
                                           const float* __restrict__ fcb,
                                           float* __restrict__ out)
{
    int b = blockIdx.x, n = blockIdx.y;
    int lane = threadIdx.x;
    const float* fb = f + (size_t)b * 16384;
    const float* wn = fcw + (size_t)n * 16384;
    float acc = 0.f;
    for (int k = lane; k < 16384; k += 64) {
        int c = k >> 6;  // channel (uniform per iteration)
        float4 s = st[c];
        float v = (fb[k] - s.x) * s.y + s.z;
        acc += v * wn[k];
    }
    for (int off = 32; off > 0; off >>= 1) acc += __shfl_down(acc, off);
    if (lane == 0) out[b * 10 + n] = acc + fcb[n];
}

extern "C" void kernel_launch(void* const* d_in, const int* in_sizes, int n_in,
                              void* d_out, int out_size, void* d_ws, size_t ws_size,
                              hipStream_t stream)
{
    const float* x    = (const float*)d_in[0];
    const float* w1   = (const float*)d_in[1];
    const float* g1   = (const float*)d_in[2];
    const float* b1   = (const float*)d_in[3];
    const float* w2_1 = (const float*)d_in[4];
    const float* g2_1 = (const float*)d_in[5];
    const float* b2_1 = (const float*)d_in[6];
    const float* w2_2 = (const float*)d_in[7];
    const float* g2_2 = (const float*)d_in[8];
    const float* b2_2 = (const float*)d_in[9];
    const float* w3_1 = (const float*)d_in[10];
    const float* g3_1 = (const float*)d_in[11];
    const float* b3_1 = (const float*)d_in[12];
    const float* w3_2 = (const float*)d_in[13];
    const float* g3_2 = (const float*)d_in[14];
    const float* b3_2 = (const float*)d_in[15];
    const float* fcw  = (const float*)d_in[16];
    const float* fcb  = (const float*)d_in[17];
    float* out = (float*)d_out;

    // workspace layout (bytes)
    const size_t OFF_BIG  = 0;                    // 134,217,728  [512,64,32,32] / [512,256,16,16] / [512,256,8,8]-x4 reuse
    const size_t OFF_P    = 134217728;            // 33,554,432   pooled
    const size_t OFF_Q    = 167772160;            // 33,554,432   gconv out
    const size_t OFF_S8   = 201326592;            // 8,388,608    sign activations
    const size_t OFF_SW22 = 209715200;            // 16,384
    const size_t OFF_SW32 = 209731584;            // 65,536
    const size_t OFF_PART = 209797120;            // 131,072
    const size_t OFF_ST   = 209928192;            // 6 * 4096
    const size_t NEED     = OFF_ST + 6 * 4096;
    if (ws_size < NEED) return;  // insufficient scratch: leave output poisoned

    char* ws = (char*)d_ws;
    float* big = (float*)(ws + OFF_BIG);
    float* p   = (float*)(ws + OFF_P);
    float* q   = (float*)(ws + OFF_Q);
    signed char* s8   = (signed char*)(ws + OFF_S8);
    signed char* sw22 = (signed char*)(ws + OFF_SW22);
    signed char* sw32 = (signed char*)(ws + OFF_SW32);
    double* part = (double*)(ws + OFF_PART);
    float4* st1  = (float4*)(ws + OFF_ST);
    float4* st21 = st1 + 256;
    float4* st22 = st21 + 256;
    float4* st31 = st22 + 256;
    float4* st32 = st31 + 256;

    // ---- layer 1 ----
    k_conv1<<<131072, 256, 0, stream>>>(x, w1, big);                       // [512,64,32,32]
    k_stats<<<dim3(64, 64), 256, 0, stream>>>(big, part, 64, 1024, 8);
    k_finalize<<<1, 256, 0, stream>>>(part, 64, 512 * 1024, g1, b1, st1, 64);
    k_bnpool<64, 32><<<32768, 256, 0, stream>>>(big, st1, p);              // [512,64,16,16]

    // ---- layer 2 ----
    k_convg<64, 16><<<32768, 256, 0, stream>>>(p, w2_1, q);                // [512,64,16,16]
    k_stats<<<dim3(64, 64), 256, 0, stream>>>(q, part, 64, 256, 8);
    k_finalize<<<1, 256, 0, stream>>>(part, 64, 512 * 256, g2_1, b2_1, st21, 64);
    k_bnbin<64, 256><<<32768, 256, 0, stream>>>(q, st21, s8);              // signs
    k_wsign<<<64, 256, 0, stream>>>(w2_2, sw22, 16384);
    k_conv1x1<64, 256, 256><<<32768, 256, 0, stream>>>(s8, sw22, big);     // [512,256,16,16]
    k_stats<<<dim3(256, 32), 256, 0, stream>>>(big, part, 256, 256, 16);
    k_finalize<<<1, 256, 0, stream>>>(part, 32, 512 * 256, g2_2, b2_2, st22, 256);
    k_bnpool<256, 16><<<32768, 256, 0, stream>>>(big, st22, p);            // [512,256,8,8]

    // ---- layer 3 ----
    k_convg<256, 8><<<32768, 256, 0, stream>>>(p, w3_1, q);                // [512,256,8,8]
    k_stats<<<dim3(256, 32), 256, 0, stream>>>(q, part, 256, 64, 16);
    k_finalize<<<1, 256, 0, stream>>>(part, 32, 512 * 64, g3_1, b3_1, st31, 256);
    k_bnbin<256, 64><<<32768, 256, 0, stream>>>(q, st31, s8);              // signs
    k_wsign<<<256, 256, 0, stream>>>(w3_2, sw32, 65536);
    k_conv1x1<256, 256, 64><<<8192, 256, 0, stream>>>(s8, sw32, big);      // [512,256,8,8]
    k_stats<<<dim3(256, 32), 256, 0, stream>>>(big, part, 256, 64, 16);
    k_finalize<<<1, 256, 0, stream>>>(part, 32, 512 * 64, g3_2, b3_2, st32, 256);

    // ---- FC (bn3_2 fused) ----
    k_fc<<<dim3(512, 10), 64, 0, stream>>>(big, st32, fcw, fcb, out);
}

// Round 2
// 905.712 us; speedup vs baseline: 1.4763x; 1.4763x over previous
//
#include <hip/hip_runtime.h>

// ---------------------------------------------------------------------------
// LiBNet forward: binarized CNN, B=512
//  conv1(3->64,4x4,pad(1,2,1,2)) -> shiftBN -> maxpool2
//  -> sign -> gconv(64,g=32,4x4,pad) -> shiftBN -> sign -> 1x1(64->256) -> shiftBN -> maxpool2
//  -> sign -> gconv(256,g=128,4x4,pad) -> shiftBN -> sign -> 1x1(256->256) -> shiftBN
//  -> FC(16384->10)
// ---------------------------------------------------------------------------

static __device__ __forceinline__ float fsign(float x) {
    return (x > 0.f) ? 1.f : ((x < 0.f) ? -1.f : 0.f);
}
static __device__ __forceinline__ int isign(float x) {
    return (x > 0.f) ? 1 : ((x < 0.f) ? -1 : 0);
}

// --- weight sign -> float (for conv1 scalar-operand FMAs) ---
__global__ void k_wsignf(const float* __restrict__ w, float* __restrict__ out, int n)
{
    int t = blockIdx.x * blockDim.x + threadIdx.x;
    if (t < n) out[t] = fsign(w[t]);
}

// --- conv1: real input [512,3,32,32], pre-signed 4x4 weights, pad(1,2,1,2) ---
// Block = quarter of one image's positions; stages padded image in LDS,
// pulls 48 taps to registers once, loops all 64 oc with scalar-weight FMAs.
__global__ __launch_bounds__(256) void k_conv1(const float* __restrict__ x,
                                               const float* __restrict__ swf,
                                               float* __restrict__ out)
{
    __shared__ float sx[3 * 35 * 35];
    int b = blockIdx.x >> 2, q = blockIdx.x & 3;
    for (int i = threadIdx.x; i < 3 * 35 * 35; i += 256) sx[i] = 0.f;
    __syncthreads();
    const float* xb = x + (size_t)b * 3072;
    for (int i = threadIdx.x; i < 3072; i += 256) {
        int w = i & 31, h = (i >> 5) & 31, ic = i >> 10;
        sx[(ic * 35 + h + 1) * 35 + w + 1] = xb[i];
    }
    __syncthreads();
    int pos = q * 256 + threadIdx.x;
    int h = pos >> 5, w = pos & 31;
    float in[48];
#pragma unroll
    for (int ic = 0; ic < 3; ++ic)
#pragma unroll
        for (int kh = 0; kh < 4; ++kh)
#pragma unroll
            for (int kw = 0; kw < 4; ++kw)
                in[ic * 16 + kh * 4 + kw] = sx[(ic * 35 + h + kh) * 35 + w + kw];
    float* op = out + (size_t)b * 64 * 1024 + pos;
#pragma unroll 4
    for (int oc = 0; oc < 64; ++oc) {
        const float* wp = swf + oc * 48;   // wave-uniform -> s_load
        float a0 = 0.f, a1 = 0.f, a2 = 0.f, a3 = 0.f;
#pragma unroll
        for (int k = 0; k < 48; k += 4) {
            a0 += in[k]     * wp[k];
            a1 += in[k + 1] * wp[k + 1];
            a2 += in[k + 2] * wp[k + 2];
            a3 += in[k + 3] * wp[k + 3];
        }
        op[(size_t)oc * 1024] = (a0 + a1) + (a2 + a3);
    }
}

// --- per-channel sum/sumsq partials (deterministic, double precision) ---
__global__ __launch_bounds__(256) void k_stats(const float* __restrict__ in,
                                               double* __restrict__ part,
                                               int C, int HW, int bPerChunk)
{
    int c = blockIdx.x;
    int chunk = blockIdx.y;
    int b0 = chunk * bPerChunk;
    double s = 0.0, sq = 0.0;
    for (int b = b0; b < b0 + bPerChunk; ++b) {
        const float* p = in + (size_t)(b * C + c) * HW;
        for (int i = threadIdx.x; i < HW; i += 256) {
            double v = (double)p[i];
            s += v; sq += v * v;
        }
    }
    __shared__ double ss[256];
    __shared__ double sb[256];
    ss[threadIdx.x] = s; sb[threadIdx.x] = sq;
    __syncthreads();
    for (int st = 128; st > 0; st >>= 1) {
        if (threadIdx.x < st) {
            ss[threadIdx.x] += ss[threadIdx.x + st];
            sb[threadIdx.x] += sb[threadIdx.x + st];
        }
        __syncthreads();
    }
    if (threadIdx.x == 0) {
        int nch = gridDim.y;
        part[(size_t)(c * nch + chunk) * 2]     = ss[0];
        part[(size_t)(c * nch + chunk) * 2 + 1] = sb[0];
    }
}

// --- finalize: mean/var -> power-of-two shift scale; st = {mean,scale,beta} ---
__global__ void k_finalize(const double* __restrict__ part, int nch, int N,
                           const float* __restrict__ gamma,
                           const float* __restrict__ beta,
                           float4* __restrict__ st, int C)
{
    int c = blockIdx.x * blockDim.x + threadIdx.x;
    if (c >= C) return;
    double s = 0.0, sq = 0.0;
    for (int i = 0; i < nch; ++i) {
        s  += part[(size_t)(c * nch + i) * 2];
        sq += part[(size_t)(c * nch + i) * 2 + 1];
    }
    double mean = s / (double)N;
    double var = sq / (double)N - mean * mean;
    float inv = gamma[c] / sqrtf((float)var + 1e-5f);
    float sh = rintf(log2f(fabsf(inv) + 1e-12f));
    sh = fminf(fmaxf(sh, -4.f), 4.f);
    float scale = copysignf(exp2f(sh), inv);
    st[c] = make_float4((float)mean, scale, beta[c], 0.f);
}

// --- bn apply + 2x2 maxpool ---
template <int C, int H>
__global__ __launch_bounds__(256) void k_bnpool(const float* __restrict__ in,
                                                const float4* __restrict__ st,
                                                float* __restrict__ out)
{
    constexpr int Ho = H / 2;
    int t = blockIdx.x * 256 + threadIdx.x;
    int ow = t % Ho; int r = t / Ho;
    int oh = r % Ho; r /= Ho;
    int c = r % C; int b = r / C;
    float4 s = st[c];
    const float* p = in + ((size_t)((b * C + c) * H + oh * 2)) * H + ow * 2;
    float v0 = (p[0]     - s.x) * s.y + s.z;
    float v1 = (p[1]     - s.x) * s.y + s.z;
    float v2 = (p[H]     - s.x) * s.y + s.z;
    float v3 = (p[H + 1] - s.x) * s.y + s.z;
    out[t] = fmaxf(fmaxf(v0, v1), fmaxf(v2, v3));
}

// --- grouped 4x4 binary conv (in_per_group=2, out_per_group=2), pad(1,2,1,2) ---
template <int C, int H>
__global__ __launch_bounds__(256) void k_convg(const float* __restrict__ in,
                                               const float* __restrict__ wg,
                                               float* __restrict__ out)
{
    __shared__ signed char sw[C * 32];
    for (int i = threadIdx.x; i < C * 32; i += 256) sw[i] = (signed char)isign(wg[i]);
    __syncthreads();
    int t = blockIdx.x * 256 + threadIdx.x;
    int w = t % H; int r = t / H;
    int h = r % H; r /= H;
    int oc = r % C; int b = r / C;
    int g = oc >> 1;
    const float* p0 = in + (size_t)(b * C + 2 * g) * H * H;
    const signed char* wp = sw + oc * 32;
    int acc = 0;
#pragma unroll
    for (int j = 0; j < 2; ++j) {
        const float* pc = p0 + j * H * H;
#pragma unroll
        for (int kh = 0; kh < 4; ++kh) {
            int ih = h - 1 + kh;
            if ((unsigned)ih < (unsigned)H) {
#pragma unroll
                for (int kw = 0; kw < 4; ++kw) {
                    int iw = w - 1 + kw;
                    if ((unsigned)iw < (unsigned)H)
                        acc += isign(pc[ih * H + iw]) * (int)wp[j * 16 + kh * 4 + kw];
                }
            }
        }
    }
    out[t] = (float)acc;
}

// --- bn apply + binarize -> int8 ---
template <int C, int HW>
__global__ __launch_bounds__(256) void k_bnbin(const float* __restrict__ in,
                                               const float4* __restrict__ st,
                                               signed char* __restrict__ out)
{
    int t = blockIdx.x * 256 + threadIdx.x;
    int c = (t / HW) % C;
    float4 s = st[c];
    float v = (in[t] - s.x) * s.y + s.z;
    out[t] = (signed char)isign(v);
}

// --- weight sign -> int8 ---
__global__ void k_wsign(const float* __restrict__ w, signed char* __restrict__ out, int n)
{
    int t = blockIdx.x * blockDim.x + threadIdx.x;
    if (t < n) out[t] = (signed char)isign(w[t]);
}

// --- 1x1 binary conv (integer GEMM). Each thread: 4 spatial positions. ---
template <int Cin, int Cout, int HW>
__global__ __launch_bounds__(256) void k_conv1x1(const signed char* __restrict__ s_in,
                                                 const signed char* __restrict__ s_w,
                                                 float* __restrict__ out)
{
    constexpr int HW4 = HW / 4;
    int t = blockIdx.x * 256 + threadIdx.x;
    int hw4 = t % HW4; int r = t / HW4;
    int oc = r % Cout; int b = r / Cout;
    const int* ip = (const int*)s_in + (size_t)b * Cin * HW4 + hw4;
    const signed char* wp = s_w + oc * Cin;
    int a0 = 0, a1 = 0, a2 = 0, a3 = 0;
#pragma unroll 4
    for (int ic = 0; ic < Cin; ++ic) {
        int v = ip[ic * HW4];
        int wv = (int)wp[ic];
        a0 += ((v << 24) >> 24) * wv;
        a1 += ((v << 16) >> 24) * wv;
        a2 += ((v << 8)  >> 24) * wv;
        a3 += (v >> 24) * wv;
    }
    float4 o = make_float4((float)a0, (float)a1, (float)a2, (float)a3);
    ((float4*)out)[t] = o;
}

// --- FC with bn3_2 fused: out[b,n] = sum_k bn(f[b,k]) * fcw[n,k] + fcb[n] ---
__global__ __launch_bounds__(64) void k_fc(const float* __restrict__ f,
                                           const float4* __restrict__ st,
                                           const float* __restrict__ fcw,
                                           const float* __restrict__ fcb,
                                           float* __restrict__ out)
{
    int b = blockIdx.x, n = blockIdx.y;
    int lane = threadIdx.x;
    const float* fb = f + (size_t)b * 16384;
    const float* wn = fcw + (size_t)n * 16384;
    float acc = 0.f;
    for (int k = lane; k < 16384; k += 64) {
        int c = k >> 6;
        float4 s = st[c];
        float v = (fb[k] - s.x) * s.y + s.z;
        acc += v * wn[k];
    }
    for (int off = 32; off > 0; off >>= 1) acc += __shfl_down(acc, off);
    if (lane == 0) out[b * 10 + n] = acc + fcb[n];
}

extern "C" void kernel_launch(void* const* d_in, const int* in_sizes, int n_in,
                              void* d_out, int out_size, void* d_ws, size_t ws_size,
                              hipStream_t stream)
{
    const float* x    = (const float*)d_in[0];
    const float* w1   = (const float*)d_in[1];
    const float* g1   = (const float*)d_in[2];
    const float* b1   = (const float*)d_in[3];
    const float* w2_1 = (const float*)d_in[4];
    const float* g2_1 = (const float*)d_in[5];
    const float* b2_1 = (const float*)d_in[6];
    const float* w2_2 = (const float*)d_in[7];
    const float* g2_2 = (const float*)d_in[8];
    const float* b2_2 = (const float*)d_in[9];
    const float* w3_1 = (const float*)d_in[10];
    const float* g3_1 = (const float*)d_in[11];
    const float* b3_1 = (const float*)d_in[12];
    const float* w3_2 = (const float*)d_in[13];
    const float* g3_2 = (const float*)d_in[14];
    const float* b3_2 = (const float*)d_in[15];
    const float* fcw  = (const float*)d_in[16];
    const float* fcb  = (const float*)d_in[17];
    float* out = (float*)d_out;

    // workspace layout (bytes)
    const size_t OFF_BIG  = 0;                    // 134,217,728
    const size_t OFF_P    = 134217728;            // 33,554,432
    const size_t OFF_Q    = 167772160;            // 33,554,432
    const size_t OFF_S8   = 201326592;            // 8,388,608
    const size_t OFF_SW22 = 209715200;            // 16,384
    const size_t OFF_SW32 = 209731584;            // 65,536
    const size_t OFF_PART = 209797120;            // 131,072
    const size_t OFF_ST   = 209928192;            // 6 * 4096
    const size_t OFF_SW1  = OFF_ST + 6 * 4096;    // 12,288 (conv1 signed weights, f32)
    const size_t NEED     = OFF_SW1 + 12288;
    if (ws_size < NEED) return;

    char* ws = (char*)d_ws;
    float* big = (float*)(ws + OFF_BIG);
    float* p   = (float*)(ws + OFF_P);
    float* q   = (float*)(ws + OFF_Q);
    signed char* s8   = (signed char*)(ws + OFF_S8);
    signed char* sw22 = (signed char*)(ws + OFF_SW22);
    signed char* sw32 = (signed char*)(ws + OFF_SW32);
    double* part = (double*)(ws + OFF_PART);
    float4* st1  = (float4*)(ws + OFF_ST);
    float4* st21 = st1 + 256;
    float4* st22 = st21 + 256;
    float4* st31 = st22 + 256;
    float4* st32 = st31 + 256;
    float* sw1f  = (float*)(ws + OFF_SW1);

    // ---- layer 1 ----
    k_wsignf<<<12, 256, 0, stream>>>(w1, sw1f, 3072);
    k_conv1<<<2048, 256, 0, stream>>>(x, sw1f, big);                       // [512,64,32,32]
    k_stats<<<dim3(64, 64), 256, 0, stream>>>(big, part, 64, 1024, 8);
    k_finalize<<<1, 256, 0, stream>>>(part, 64, 512 * 1024, g1, b1, st1, 64);
    k_bnpool<64, 32><<<32768, 256, 0, stream>>>(big, st1, p);              // [512,64,16,16]

    // ---- layer 2 ----
    k_convg<64, 16><<<32768, 256, 0, stream>>>(p, w2_1, q);                // [512,64,16,16]
    k_stats<<<dim3(64, 64), 256, 0, stream>>>(q, part, 64, 256, 8);
    k_finalize<<<1, 256, 0, stream>>>(part, 64, 512 * 256, g2_1, b2_1, st21, 64);
    k_bnbin<64, 256><<<32768, 256, 0, stream>>>(q, st21, s8);              // signs
    k_wsign<<<64, 256, 0, stream>>>(w2_2, sw22, 16384);
    k_conv1x1<64, 256, 256><<<32768, 256, 0, stream>>>(s8, sw22, big);     // [512,256,16,16]
    k_stats<<<dim3(256, 32), 256, 0, stream>>>(big, part, 256, 256, 16);
    k_finalize<<<1, 256, 0, stream>>>(part, 32, 512 * 256, g2_2, b2_2, st22, 256);
    k_bnpool<256, 16><<<32768, 256, 0, stream>>>(big, st22, p);            // [512,256,8,8]

    // ---- layer 3 ----
    k_convg<256, 8><<<32768, 256, 0, stream>>>(p, w3_1, q);                // [512,256,8,8]
    k_stats<<<dim3(256, 32), 256, 0, stream>>>(q, part, 256, 64, 16);
    k_finalize<<<1, 256, 0, stream>>>(part, 32, 512 * 64, g3_1, b3_1, st31, 256);
    k_bnbin<256, 64><<<32768, 256, 0, stream>>>(q, st31, s8);              // signs
    k_wsign<<<256, 256, 0, stream>>>(w3_2, sw32, 65536);
    k_conv1x1<256, 256, 64><<<8192, 256, 0, stream>>>(s8, sw32, big);      // [512,256,8,8]
    k_stats<<<dim3(256, 32), 256, 0, stream>>>(big, part, 256, 64, 16);
    k_finalize<<<1, 256, 0, stream>>>(part, 32, 512 * 64, g3_2, b3_2, st32, 256);

    // ---- FC (bn3_2 fused) ----
    k_fc<<<dim3(512, 10), 64, 0, stream>>>(big, st32, fcw, fcb, out);
}

// Round 3
// 696.098 us; speedup vs baseline: 1.9208x; 1.3011x over previous
//
#include <hip/hip_runtime.h>

typedef unsigned int u32;

// ---------------------------------------------------------------------------
// LiBNet forward, bit-packed ternary arithmetic.
// dot over taps = popc(nzA & nzW) - 2*popc((sA ^ sW) & nzA & nzW)
// nz masks preserve sign(0)=0 semantics exactly (padding AND exact zeros).
// ---------------------------------------------------------------------------

static __device__ __forceinline__ float fsign(float x) {
    return (x > 0.f) ? 1.f : ((x < 0.f) ? -1.f : 0.f);
}

// --- weight sign -> float (conv1 scalar-operand FMAs) ---
__global__ void k_wsignf(const float* __restrict__ w, float* __restrict__ out, int n)
{
    int t = blockIdx.x * blockDim.x + threadIdx.x;
    if (t < n) out[t] = fsign(w[t]);
}

// --- conv1: real input [512,3,32,32], pre-signed 4x4 weights, pad(1,2,1,2) ---
__global__ __launch_bounds__(256) void k_conv1(const float* __restrict__ x,
                                               const float* __restrict__ swf,
                                               float* __restrict__ out)
{
    __shared__ float sx[3 * 35 * 35];
    int b = blockIdx.x >> 2, q = blockIdx.x & 3;
    for (int i = threadIdx.x; i < 3 * 35 * 35; i += 256) sx[i] = 0.f;
    __syncthreads();
    const float* xb = x + (size_t)b * 3072;
    for (int i = threadIdx.x; i < 3072; i += 256) {
        int w = i & 31, h = (i >> 5) & 31, ic = i >> 10;
        sx[(ic * 35 + h + 1) * 35 + w + 1] = xb[i];
    }
    __syncthreads();
    int pos = q * 256 + threadIdx.x;
    int h = pos >> 5, w = pos & 31;
    float in[48];
#pragma unroll
    for (int ic = 0; ic < 3; ++ic)
#pragma unroll
        for (int kh = 0; kh < 4; ++kh)
#pragma unroll
            for (int kw = 0; kw < 4; ++kw)
                in[ic * 16 + kh * 4 + kw] = sx[(ic * 35 + h + kh) * 35 + w + kw];
    float* op = out + (size_t)b * 64 * 1024 + pos;
#pragma unroll 4
    for (int oc = 0; oc < 64; ++oc) {
        const float* wp = swf + oc * 48;   // wave-uniform -> s_load
        float a0 = 0.f, a1 = 0.f, a2 = 0.f, a3 = 0.f;
#pragma unroll
        for (int k = 0; k < 48; k += 4) {
            a0 += in[k]     * wp[k];
            a1 += in[k + 1] * wp[k + 1];
            a2 += in[k + 2] * wp[k + 2];
            a3 += in[k + 3] * wp[k + 3];
        }
        op[(size_t)oc * 1024] = (a0 + a1) + (a2 + a3);
    }
}

// --- per-channel sum/sumsq partials (deterministic, double precision) ---
__global__ __launch_bounds__(256) void k_stats(const float* __restrict__ in,
                                               double* __restrict__ part,
                                               int C, int HW, int bPerChunk)
{
    int c = blockIdx.x;
    int chunk = blockIdx.y;
    int b0 = chunk * bPerChunk;
    double s = 0.0, sq = 0.0;
    for (int b = b0; b < b0 + bPerChunk; ++b) {
        const float* p = in + (size_t)(b * C + c) * HW;
        for (int i = threadIdx.x; i < HW; i += 256) {
            double v = (double)p[i];
            s += v; sq += v * v;
        }
    }
    __shared__ double ss[256];
    __shared__ double sb[256];
    ss[threadIdx.x] = s; sb[threadIdx.x] = sq;
    __syncthreads();
    for (int st = 128; st > 0; st >>= 1) {
        if (threadIdx.x < st) {
            ss[threadIdx.x] += ss[threadIdx.x + st];
            sb[threadIdx.x] += sb[threadIdx.x + st];
        }
        __syncthreads();
    }
    if (threadIdx.x == 0) {
        int nch = gridDim.y;
        part[(size_t)(c * nch + chunk) * 2]     = ss[0];
        part[(size_t)(c * nch + chunk) * 2 + 1] = sb[0];
    }
}

// --- finalize: mean/var -> power-of-two shift scale; st = {mean,scale,beta} ---
__global__ void k_finalize(const double* __restrict__ part, int nch, int N,
                           const float* __restrict__ gamma,
                           const float* __restrict__ beta,
                           float4* __restrict__ st, int C)
{
    int c = blockIdx.x * blockDim.x + threadIdx.x;
    if (c >= C) return;
    double s = 0.0, sq = 0.0;
    for (int i = 0; i < nch; ++i) {
        s  += part[(size_t)(c * nch + i) * 2];
        sq += part[(size_t)(c * nch + i) * 2 + 1];
    }
    double mean = s / (double)N;
    double var = sq / (double)N - mean * mean;
    float inv = gamma[c] / sqrtf((float)var + 1e-5f);
    float sh = rintf(log2f(fabsf(inv) + 1e-12f));
    sh = fminf(fmaxf(sh, -4.f), 4.f);
    float scale = copysignf(exp2f(sh), inv);
    st[c] = make_float4((float)mean, scale, beta[c], 0.f);
}

// --- bn + 2x2 maxpool + binarize + row-bitpack (19-bit padded rows) ---
// Output row slot i holds input row ih=i-1; bit j holds column iw=j-1.
// Margin slots / bits are zero => pad contributes nothing via nz mask.
template <int C, int H>  // H = input height; pooled Ho=H/2
__global__ __launch_bounds__(256) void k_poolpack(const float* __restrict__ in,
                                                  const float4* __restrict__ st,
                                                  u32* __restrict__ spk,
                                                  u32* __restrict__ npk)
{
    constexpr int Ho = H / 2;
    constexpr int SLOTS = (Ho == 16) ? 20 : 12;
    int t = blockIdx.x * 256 + threadIdx.x;
    int oh = t % Ho; int r0 = t / Ho;
    int c = r0 % C; int b = r0 / C;
    float4 s = st[c];
    const float* p0 = in + ((size_t)((b * C + c) * H + 2 * oh)) * H;
    bool pos = (s.y > 0.f);   // bn scale sign: pool with max if >0 else min
    u32 sb = 0, nb = 0;
#pragma unroll
    for (int ow = 0; ow < Ho; ++ow) {
        float a0 = p0[2 * ow], a1 = p0[2 * ow + 1];
        float a2 = p0[H + 2 * ow], a3 = p0[H + 2 * ow + 1];
        float raw = pos ? fmaxf(fmaxf(a0, a1), fmaxf(a2, a3))
                        : fminf(fminf(a0, a1), fminf(a2, a3));
        float v = (raw - s.x) * s.y + s.z;
        sb |= (u32)(v > 0.f) << (ow + 1);
        nb |= (u32)(v != 0.f) << (ow + 1);
    }
    size_t base = (size_t)(b * C + c) * SLOTS;
    spk[base + oh + 1] = sb;
    npk[base + oh + 1] = nb;
    if (oh < 4) {  // zero the margin slots (0 and Ho+1..SLOTS-1)
        int zs = (oh == 0) ? 0 : (Ho + oh);
        spk[base + zs] = 0; npk[base + zs] = 0;
    }
}

// --- grouped 4x4 weights -> per-(oc,ic,kh) nibbles: sign | nz<<8 ---
template <int C>
__global__ void k_wpackg(const float* __restrict__ w, u32* __restrict__ wpk)
{
    int oc = blockIdx.x * blockDim.x + threadIdx.x;
    if (oc >= C) return;
    const float* p = w + oc * 32;
#pragma unroll
    for (int r = 0; r < 8; ++r) {           // r = ic*4 + kh
        u32 sn = 0, nz = 0;
#pragma unroll
        for (int kw = 0; kw < 4; ++kw) {
            float v = p[r * 4 + kw];
            sn |= (u32)(v > 0.f) << kw;
            nz |= (u32)(v != 0.f) << kw;
        }
        wpk[oc * 8 + r] = sn | (nz << 8);
    }
}

// --- grouped 4x4 binary conv, bit-packed. Thread = (b, group, out-row). ---
template <int C, int H>
__global__ __launch_bounds__(256) void k_convg_bp(const u32* __restrict__ spk,
                                                  const u32* __restrict__ npk,
                                                  const u32* __restrict__ wpk,
                                                  float* __restrict__ out)
{
    constexpr int SLOTS = (H == 16) ? 20 : 12;
    int t = blockIdx.x * 256 + threadIdx.x;
    int h = t % H; int r0 = t / H;
    int g = r0 % (C / 2); int b = r0 / (C / 2);
    const u32* sp = spk + (size_t)(b * C + 2 * g) * SLOTS + h;
    const u32* np = npk + (size_t)(b * C + 2 * g) * SLOTS + h;
    u32 S[8], N[8];
#pragma unroll
    for (int jc = 0; jc < 2; ++jc)
#pragma unroll
        for (int jj = 0; jj < 4; ++jj) {    // slot h+jj = input row h-1+jj (kh=jj)
            S[jc * 4 + jj] = sp[jc * SLOTS + jj];
            N[jc * 4 + jj] = np[jc * SLOTS + jj];
        }
    const u32* wq = wpk + (size_t)(2 * g) * 8;
    u32 Ws0[8], Wn0[8], Ws1[8], Wn1[8];
#pragma unroll
    for (int r = 0; r < 8; ++r) {
        u32 a = wq[r];      Ws0[r] = a & 15u;  Wn0[r] = (a >> 8) & 15u;
        u32 bb = wq[8 + r]; Ws1[r] = bb & 15u; Wn1[r] = (bb >> 8) & 15u;
    }
    float v0[H], v1[H];
#pragma unroll
    for (int w = 0; w < H; ++w) {
        int snz0 = 0, smis0 = 0, snz1 = 0, smis1 = 0;
#pragma unroll
        for (int r = 0; r < 8; ++r) {
            u32 ss = (S[r] >> w) & 15u;     // taps iw = w-1..w+2
            u32 nn = (N[r] >> w) & 15u;
            u32 nz0 = nn & Wn0[r]; u32 m0 = (ss ^ Ws0[r]) & nz0;
            snz0 += __popc(nz0); smis0 += __popc(m0);
            u32 nz1 = nn & Wn1[r]; u32 m1 = (ss ^ Ws1[r]) & nz1;
            snz1 += __popc(nz1); smis1 += __popc(m1);
        }
        v0[w] = (float)(snz0 - 2 * smis0);
        v1[w] = (float)(snz1 - 2 * smis1);
    }
    float* o0 = out + ((size_t)((b * C + 2 * g) * H + h)) * H;
    float* o1 = o0 + (size_t)H * H;
#pragma unroll
    for (int w4 = 0; w4 < H / 4; ++w4) {
        ((float4*)o0)[w4] = make_float4(v0[4*w4], v0[4*w4+1], v0[4*w4+2], v0[4*w4+3]);
        ((float4*)o1)[w4] = make_float4(v1[4*w4], v1[4*w4+1], v1[4*w4+2], v1[4*w4+3]);
    }
}

// --- bn + binarize + channel-bitpack: act[b*HW+hw][0..W-1]=sign, [W..2W-1]=nz ---
template <int C, int HW>
__global__ __launch_bounds__(256) void k_bnpackC(const float* __restrict__ q,
                                                 const float4* __restrict__ st,
                                                 u32* __restrict__ act)
{
    constexpr int W = C / 32;
    int t = blockIdx.x * 256 + threadIdx.x;   // t = b*HW + hw
    int hw = t % HW; int b = t / HW;
    const float* qp = q + (size_t)b * C * HW + hw;
    u32* ap = act + (size_t)t * 2 * W;
#pragma unroll
    for (int j = 0; j < W; ++j) {
        u32 sv = 0, nv = 0;
#pragma unroll
        for (int k = 0; k < 32; ++k) {
            int c = j * 32 + k;
            float4 s = st[c];
            float v = (qp[(size_t)c * HW] - s.x) * s.y + s.z;
            sv |= (u32)(v > 0.f) << k;
            nv |= (u32)(v != 0.f) << k;
        }
        ap[j] = sv; ap[W + j] = nv;
    }
}

// --- 1x1 weights -> packed words: [oc][0..W-1]=sign, [W..2W-1]=nz ---
template <int Cout, int Cin>
__global__ void k_wpack1x1(const float* __restrict__ w, u32* __restrict__ wp)
{
    constexpr int W = Cin / 32;
    int oc = blockIdx.x * blockDim.x + threadIdx.x;
    if (oc >= Cout) return;
    const float* p = w + (size_t)oc * Cin;
#pragma unroll
    for (int j = 0; j < W; ++j) {
        u32 sv = 0, nv = 0;
#pragma unroll
        for (int k = 0; k < 32; ++k) {
            float v = p[j * 32 + k];
            sv |= (u32)(v > 0.f) << k;
            nv |= (u32)(v != 0.f) << k;
        }
        wp[(size_t)oc * 2 * W + j] = sv;
        wp[(size_t)oc * 2 * W + W + j] = nv;
    }
}

// --- 1x1 conv, Cin=64 (W=2), Cout=256, HW=256. Thread = (b,hw), all oc. ---
__global__ __launch_bounds__(256) void k_conv1x1_bp2(const u32* __restrict__ act,
                                                     const u32* __restrict__ wp,
                                                     float* __restrict__ out)
{
    int t = blockIdx.x * 256 + threadIdx.x;   // t = b*256 + hw
    int hw = t & 255; int b = t >> 8;
    uint4 av = ((const uint4*)act)[t];        // s0,s1,n0,n1
    float* op = out + (size_t)b * 256 * 256 + hw;
#pragma unroll 8
    for (int oc = 0; oc < 256; ++oc) {
        uint4 wv = ((const uint4*)wp)[oc];    // wave-uniform -> scalar loads
        u32 nz0 = av.z & wv.z, nz1 = av.w & wv.w;
        u32 m0 = (av.x ^ wv.x) & nz0, m1 = (av.y ^ wv.y) & nz1;
        int dot = __popc(nz0) + __popc(nz1) - 2 * (__popc(m0) + __popc(m1));
        op[(size_t)oc << 8] = (float)dot;
    }
}

// --- 1x1 conv, Cin=256 (W=8), Cout=256 in 4 chunks, HW=64. ---
__global__ __launch_bounds__(256) void k_conv1x1_bp3(const u32* __restrict__ act,
                                                     const u32* __restrict__ wp,
                                                     float* __restrict__ out)
{
    int t = blockIdx.x * 256 + threadIdx.x;
    int hw = t & 63; int ch = (t >> 6) & 3; int b = t >> 8;
    const u32* ap = act + (size_t)(b * 64 + hw) * 16;
    u32 as[8], an[8];
#pragma unroll
    for (int j = 0; j < 8; ++j) { as[j] = ap[j]; an[j] = ap[8 + j]; }
    float* op = out + (size_t)b * 256 * 64 + hw;
#pragma unroll 4
    for (int oc = ch * 64; oc < ch * 64 + 64; ++oc) {
        const u32* wq = wp + oc * 16;
        int snz = 0, smis = 0;
#pragma unroll
        for (int j = 0; j < 8; ++j) {
            u32 nz = an[j] & wq[8 + j];
            u32 m = (as[j] ^ wq[j]) & nz;
            snz += __popc(nz); smis += __popc(m);
        }
        op[(size_t)oc * 64] = (float)(snz - 2 * smis);
    }
}

// --- FC with bn3_2 fused ---
__global__ __launch_bounds__(64) void k_fc(const float* __restrict__ f,
                                           const float4* __restrict__ st,
                                           const float* __restrict__ fcw,
                                           const float* __restrict__ fcb,
                                           float* __restrict__ out)
{
    int b = blockIdx.x, n = blockIdx.y;
    int lane = threadIdx.x;
    const float* fb = f + (size_t)b * 16384;
    const float* wn = fcw + (size_t)n * 16384;
    float acc = 0.f;
    for (int k = lane; k < 16384; k += 64) {
        int c = k >> 6;
        float4 s = st[c];
        float v = (fb[k] - s.x) * s.y + s.z;
        acc += v * wn[k];
    }
    for (int off = 32; off > 0; off >>= 1) acc += __shfl_down(acc, off);
    if (lane == 0) out[b * 10 + n] = acc + fcb[n];
}

extern "C" void kernel_launch(void* const* d_in, const int* in_sizes, int n_in,
                              void* d_out, int out_size, void* d_ws, size_t ws_size,
                              hipStream_t stream)
{
    const float* x    = (const float*)d_in[0];
    const float* w1   = (const float*)d_in[1];
    const float* g1   = (const float*)d_in[2];
    const float* b1   = (const float*)d_in[3];
    const float* w2_1 = (const float*)d_in[4];
    const float* g2_1 = (const float*)d_in[5];
    const float* b2_1 = (const float*)d_in[6];
    const float* w2_2 = (const float*)d_in[7];
    const float* g2_2 = (const float*)d_in[8];
    const float* b2_2 = (const float*)d_in[9];
    const float* w3_1 = (const float*)d_in[10];
    const float* g3_1 = (const float*)d_in[11];
    const float* b3_1 = (const float*)d_in[12];
    const float* w3_2 = (const float*)d_in[13];
    const float* g3_2 = (const float*)d_in[14];
    const float* b3_2 = (const float*)d_in[15];
    const float* fcw  = (const float*)d_in[16];
    const float* fcb  = (const float*)d_in[17];
    float* out = (float*)d_out;

    // workspace layout (bytes)
    const size_t OFF_BIG   = 0;           // 134,217,728 (conv1 / conv2_2 / conv3_2 outs)
    const size_t OFF_Q     = 134217728;   // 33,554,432  (convg outs, both layers)
    const size_t OFF_SPK2  = 167772160;   // 2,621,440   [512][64][20]
    const size_t OFF_NPK2  = 170393600;   // 2,621,440
    const size_t OFF_SPK3  = 173015040;   // 6,291,456   [512][256][12]
    const size_t OFF_NPK3  = 179306496;   // 6,291,456
    const size_t OFF_A     = 185597952;   // 2,097,152   packed acts (reused L2/L3)
    const size_t OFF_WPK21 = 187695104;   // 2,048
    const size_t OFF_WPK31 = 187697152;   // 8,192
    const size_t OFF_WP22  = 187705344;   // 4,096
    const size_t OFF_WP32  = 187709440;   // 16,384
    const size_t OFF_PART  = 187725824;   // 131,072
    const size_t OFF_ST    = 187856896;   // 24,576
    const size_t OFF_SW1   = 187881472;   // 12,288
    const size_t NEED      = OFF_SW1 + 12288;
    if (ws_size < NEED) return;

    char* ws = (char*)d_ws;
    float* big = (float*)(ws + OFF_BIG);
    float* q   = (float*)(ws + OFF_Q);
    u32* spk2  = (u32*)(ws + OFF_SPK2);
    u32* npk2  = (u32*)(ws + OFF_NPK2);
    u32* spk3  = (u32*)(ws + OFF_SPK3);
    u32* npk3  = (u32*)(ws + OFF_NPK3);
    u32* actA  = (u32*)(ws + OFF_A);
    u32* wpk21 = (u32*)(ws + OFF_WPK21);
    u32* wpk31 = (u32*)(ws + OFF_WPK31);
    u32* wp22  = (u32*)(ws + OFF_WP22);
    u32* wp32  = (u32*)(ws + OFF_WP32);
    double* part = (double*)(ws + OFF_PART);
    float4* st1  = (float4*)(ws + OFF_ST);
    float4* st21 = st1 + 256;
    float4* st22 = st21 + 256;
    float4* st31 = st22 + 256;
    float4* st32 = st31 + 256;
    float* sw1f  = (float*)(ws + OFF_SW1);

    // ---- layer 1 ----
    k_wsignf<<<12, 256, 0, stream>>>(w1, sw1f, 3072);
    k_conv1<<<2048, 256, 0, stream>>>(x, sw1f, big);                     // [512,64,32,32]
    k_stats<<<dim3(64, 64), 256, 0, stream>>>(big, part, 64, 1024, 8);
    k_finalize<<<1, 256, 0, stream>>>(part, 64, 512 * 1024, g1, b1, st1, 64);
    k_poolpack<64, 32><<<2048, 256, 0, stream>>>(big, st1, spk2, npk2);  // packed 16x16

    // ---- layer 2 ----
    k_wpackg<64><<<1, 64, 0, stream>>>(w2_1, wpk21);
    k_convg_bp<64, 16><<<1024, 256, 0, stream>>>(spk2, npk2, wpk21, q);  // [512,64,16,16]
    k_stats<<<dim3(64, 64), 256, 0, stream>>>(q, part, 64, 256, 8);
    k_finalize<<<1, 256, 0, stream>>>(part, 64, 512 * 256, g2_1, b2_1, st21, 64);
    k_bnpackC<64, 256><<<512, 256, 0, stream>>>(q, st21, actA);
    k_wpack1x1<256, 64><<<1, 256, 0, stream>>>(w2_2, wp22);
    k_conv1x1_bp2<<<512, 256, 0, stream>>>(actA, wp22, big);             // [512,256,16,16]
    k_stats<<<dim3(256, 32), 256, 0, stream>>>(big, part, 256, 256, 16);
    k_finalize<<<1, 256, 0, stream>>>(part, 32, 512 * 256, g2_2, b2_2, st22, 256);
    k_poolpack<256, 16><<<4096, 256, 0, stream>>>(big, st22, spk3, npk3); // packed 8x8

    // ---- layer 3 ----
    k_wpackg<256><<<1, 256, 0, stream>>>(w3_1, wpk31);
    k_convg_bp<256, 8><<<2048, 256, 0, stream>>>(spk3, npk3, wpk31, q);  // [512,256,8,8]
    k_stats<<<dim3(256, 32), 256, 0, stream>>>(q, part, 256, 64, 16);
    k_finalize<<<1, 256, 0, stream>>>(part, 32, 512 * 64, g3_1, b3_1, st31, 256);
    k_bnpackC<256, 64><<<128, 256, 0, stream>>>(q, st31, actA);
    k_wpack1x1<256, 256><<<1, 256, 0, stream>>>(w3_2, wp32);
    k_conv1x1_bp3<<<512, 256, 0, stream>>>(actA, wp32, big);             // [512,256,8,8]
    k_stats<<<dim3(256, 32), 256, 0, stream>>>(big, part, 256, 64, 16);
    k_finalize<<<1, 256, 0, stream>>>(part, 32, 512 * 64, g3_2, b3_2, st32, 256);

    // ---- FC (bn3_2 fused) ----
    k_fc<<<dim3(512, 10), 64, 0, stream>>>(big, st32, fcw, fcb, out);
}

// Round 4
// 479.309 us; speedup vs baseline: 2.7896x; 1.4523x over previous
//
#include <hip/hip_runtime.h>

typedef unsigned int u32;

// ---------------------------------------------------------------------------
// LiBNet forward, bit-packed ternary arithmetic + integer intermediates.
// dot over taps = popc(nzA & nzW) - 2*popc((sA ^ sW) & nzA & nzW)
// nz masks preserve sign(0)=0 semantics exactly (padding AND exact zeros).
// Binary-conv outputs are exact small ints -> int8/int16 storage.
// ---------------------------------------------------------------------------

static __device__ __forceinline__ float fsign(float x) {
    return (x > 0.f) ? 1.f : ((x < 0.f) ? -1.f : 0.f);
}
static __device__ __forceinline__ u32 pack4(int a, int b, int c, int d) {
    return (a & 0xff) | ((b & 0xff) << 8) | ((c & 0xff) << 16) | ((u32)(d & 0xff) << 24);
}

// --- weight sign -> float (conv1 scalar-operand FMAs) ---
__global__ void k_wsignf(const float* __restrict__ w, float* __restrict__ out, int n)
{
    int t = blockIdx.x * blockDim.x + threadIdx.x;
    if (t < n) out[t] = fsign(w[t]);
}

// --- conv1: real input [512,3,32,32], pre-signed 4x4 weights, pad(1,2,1,2) ---
__global__ __launch_bounds__(256) void k_conv1(const float* __restrict__ x,
                                               const float* __restrict__ swf,
                                               float* __restrict__ out)
{
    __shared__ float sx[3 * 35 * 35];
    int b = blockIdx.x >> 2, q = blockIdx.x & 3;
    for (int i = threadIdx.x; i < 3 * 35 * 35; i += 256) sx[i] = 0.f;
    __syncthreads();
    const float* xb = x + (size_t)b * 3072;
    for (int i = threadIdx.x; i < 3072; i += 256) {
        int w = i & 31, h = (i >> 5) & 31, ic = i >> 10;
        sx[(ic * 35 + h + 1) * 35 + w + 1] = xb[i];
    }
    __syncthreads();
    int pos = q * 256 + threadIdx.x;
    int h = pos >> 5, w = pos & 31;
    float in[48];
#pragma unroll
    for (int ic = 0; ic < 3; ++ic)
#pragma unroll
        for (int kh = 0; kh < 4; ++kh)
#pragma unroll
            for (int kw = 0; kw < 4; ++kw)
                in[ic * 16 + kh * 4 + kw] = sx[(ic * 35 + h + kh) * 35 + w + kw];
    float* op = out + (size_t)b * 64 * 1024 + pos;
#pragma unroll 4
    for (int oc = 0; oc < 64; ++oc) {
        const float* wp = swf + oc * 48;   // wave-uniform -> s_load
        float a0 = 0.f, a1 = 0.f, a2 = 0.f, a3 = 0.f;
#pragma unroll
        for (int k = 0; k < 48; k += 4) {
            a0 += in[k]     * wp[k];
            a1 += in[k + 1] * wp[k + 1];
            a2 += in[k + 2] * wp[k + 2];
            a3 += in[k + 3] * wp[k + 3];
        }
        op[(size_t)oc * 1024] = (a0 + a1) + (a2 + a3);
    }
}

// --- f32 stats, float4 loads (conv1 output), deterministic double partials ---
__global__ __launch_bounds__(256) void k_statsf4(const float* __restrict__ in,
                                                 double* __restrict__ part,
                                                 int C, int HW, int bPerChunk)
{
    int c = blockIdx.x, chunk = blockIdx.y, b0 = chunk * bPerChunk;
    int q4 = HW >> 2;
    double s = 0.0, sq = 0.0;
    for (int b = b0; b < b0 + bPerChunk; ++b) {
        const float4* p = (const float4*)(in + (size_t)(b * C + c) * HW);
        for (int i = threadIdx.x; i < q4; i += 256) {
            float4 v = p[i];
            s  += (double)v.x + (double)v.y + (double)v.z + (double)v.w;
            sq += (double)v.x * v.x + (double)v.y * v.y
                + (double)v.z * v.z + (double)v.w * v.w;
        }
    }
    __shared__ double ss[256];
    __shared__ double sb[256];
    ss[threadIdx.x] = s; sb[threadIdx.x] = sq;
    __syncthreads();
    for (int st = 128; st > 0; st >>= 1) {
        if (threadIdx.x < st) {
            ss[threadIdx.x] += ss[threadIdx.x + st];
            sb[threadIdx.x] += sb[threadIdx.x + st];
        }
        __syncthreads();
    }
    if (threadIdx.x == 0) {
        int nch = gridDim.y;
        part[(size_t)(c * nch + chunk) * 2]     = ss[0];
        part[(size_t)(c * nch + chunk) * 2 + 1] = sb[0];
    }
}

// --- int8 stats: exact int32 block sums -> double partials ---
__global__ __launch_bounds__(256) void k_stats_i8(const signed char* __restrict__ in,
                                                  double* __restrict__ part,
                                                  int C, int HW, int bPerChunk)
{
    int c = blockIdx.x, chunk = blockIdx.y, b0 = chunk * bPerChunk;
    int q4 = HW >> 2;
    int s = 0, sq = 0;
    for (int b = b0; b < b0 + bPerChunk; ++b) {
        const u32* p = (const u32*)(in + (size_t)(b * C + c) * HW);
        for (int i = threadIdx.x; i < q4; i += 256) {
            u32 v = p[i];
            int x0 = (int)(v << 24) >> 24, x1 = (int)(v << 16) >> 24;
            int x2 = (int)(v << 8) >> 24,  x3 = (int)v >> 24;
            s += x0 + x1 + x2 + x3;
            sq += x0 * x0 + x1 * x1 + x2 * x2 + x3 * x3;
        }
    }
    __shared__ int ss[256];
    __shared__ int sb[256];
    ss[threadIdx.x] = s; sb[threadIdx.x] = sq;
    __syncthreads();
    for (int st = 128; st > 0; st >>= 1) {
        if (threadIdx.x < st) {
            ss[threadIdx.x] += ss[threadIdx.x + st];
            sb[threadIdx.x] += sb[threadIdx.x + st];
        }
        __syncthreads();
    }
    if (threadIdx.x == 0) {
        int nch = gridDim.y;
        part[(size_t)(c * nch + chunk) * 2]     = (double)ss[0];
        part[(size_t)(c * nch + chunk) * 2 + 1] = (double)sb[0];
    }
}

// --- int16 stats ---
__global__ __launch_bounds__(256) void k_stats_i16(const short* __restrict__ in,
                                                   double* __restrict__ part,
                                                   int C, int HW, int bPerChunk)
{
    int c = blockIdx.x, chunk = blockIdx.y, b0 = chunk * bPerChunk;
    int q2 = HW >> 1;
    int s = 0, sq = 0;
    for (int b = b0; b < b0 + bPerChunk; ++b) {
        const u32* p = (const u32*)(in + (size_t)(b * C + c) * HW);
        for (int i = threadIdx.x; i < q2; i += 256) {
            u32 v = p[i];
            int x0 = (int)(v << 16) >> 16, x1 = (int)v >> 16;
            s += x0 + x1;
            sq += x0 * x0 + x1 * x1;
        }
    }
    __shared__ int ss[256];
    __shared__ int sb[256];
    ss[threadIdx.x] = s; sb[threadIdx.x] = sq;
    __syncthreads();
    for (int st = 128; st > 0; st >>= 1) {
        if (threadIdx.x < st) {
            ss[threadIdx.x] += ss[threadIdx.x + st];
            sb[threadIdx.x] += sb[threadIdx.x + st];
        }
        __syncthreads();
    }
    if (threadIdx.x == 0) {
        int nch = gridDim.y;
        part[(size_t)(c * nch + chunk) * 2]     = (double)ss[0];
        part[(size_t)(c * nch + chunk) * 2 + 1] = (double)sb[0];
    }
}

// --- finalize: mean/var -> power-of-two shift scale; st = {mean,scale,beta} ---
__global__ void k_finalize(const double* __restrict__ part, int nch, int N,
                           const float* __restrict__ gamma,
                           const float* __restrict__ beta,
                           float4* __restrict__ st, int C)
{
    int c = blockIdx.x * blockDim.x + threadIdx.x;
    if (c >= C) return;
    double s = 0.0, sq = 0.0;
    for (int i = 0; i < nch; ++i) {
        s  += part[(size_t)(c * nch + i) * 2];
        sq += part[(size_t)(c * nch + i) * 2 + 1];
    }
    double mean = s / (double)N;
    double var = sq / (double)N - mean * mean;
    float inv = gamma[c] / sqrtf((float)var + 1e-5f);
    float sh = rintf(log2f(fabsf(inv) + 1e-12f));
    sh = fminf(fmaxf(sh, -4.f), 4.f);
    float scale = copysignf(exp2f(sh), inv);
    st[c] = make_float4((float)mean, scale, beta[c], 0.f);
}

// --- layer1 bn+pool+pack: f32 in [512,64,32,32], coalesced, ballot-packed ---
// Block = one (b,c); wave w handles oh = w*4+r (r=lane>>4), ow = lane&15.
__global__ __launch_bounds__(256) void k_poolpack1(const float* __restrict__ in,
                                                   const float4* __restrict__ st,
                                                   u32* __restrict__ spk,
                                                   u32* __restrict__ npk)
{
    int bc = blockIdx.x;              // b*64 + c
    int c = bc & 63;
    int lane = threadIdx.x & 63, wv = threadIdx.x >> 6;
    int r = lane >> 4, ow = lane & 15;
    int oh = wv * 4 + r;
    float4 s = st[c];
    const float* p = in + (size_t)bc * 1024 + (2 * oh) * 32 + 2 * ow;
    float2 a01 = *(const float2*)p;
    float2 a23 = *(const float2*)(p + 32);
    bool pos = (s.y > 0.f);
    float raw = pos ? fmaxf(fmaxf(a01.x, a01.y), fmaxf(a23.x, a23.y))
                    : fminf(fminf(a01.x, a01.y), fminf(a23.x, a23.y));
    float v = (raw - s.x) * s.y + s.z;
    unsigned long long bs = __ballot(v > 0.f);
    unsigned long long bn = __ballot(v != 0.f);
    size_t base = (size_t)bc * 20;
    if (ow == 0) {
        spk[base + 1 + oh] = (((u32)(bs >> (16 * r))) & 0xffffu) << 1;
        npk[base + 1 + oh] = (((u32)(bn >> (16 * r))) & 0xffffu) << 1;
    }
    if (threadIdx.x < 4) {            // zero margin slots 0,17,18,19
        int zs = (threadIdx.x == 0) ? 0 : (16 + threadIdx.x);
        spk[base + zs] = 0; npk[base + zs] = 0;
    }
}

// --- layer2->3 bn+pool+pack: int8 in [512,256,16,16], wave per channel ---
__global__ __launch_bounds__(256) void k_poolpack3(const signed char* __restrict__ in,
                                                   const float4* __restrict__ st,
                                                   u32* __restrict__ spk,
                                                   u32* __restrict__ npk)
{
    int wv = threadIdx.x >> 6, lane = threadIdx.x & 63;
    int bc = blockIdx.x * 4 + wv;     // b*256 + c
    int c = bc & 255;
    int oh = lane >> 3, ow = lane & 7;
    float4 s = st[c];
    const signed char* p = in + (size_t)bc * 256 + (2 * oh) * 16 + 2 * ow;
    short s01 = *(const short*)p;
    short s23 = *(const short*)(p + 16);
    int a0 = (int)(signed char)(s01 & 0xff), a1 = (int)(s01 >> 8);
    int a2 = (int)(signed char)(s23 & 0xff), a3 = (int)(s23 >> 8);
    bool pos = (s.y > 0.f);
    int raw = pos ? max(max(a0, a1), max(a2, a3)) : min(min(a0, a1), min(a2, a3));
    float v = ((float)raw - s.x) * s.y + s.z;
    unsigned long long bs = __ballot(v > 0.f);
    unsigned long long bn = __ballot(v != 0.f);
    size_t base = (size_t)bc * 12;
    if (ow == 0) {
        spk[base + 1 + oh] = (((u32)(bs >> (8 * oh))) & 0xffu) << 1;
        npk[base + 1 + oh] = (((u32)(bn >> (8 * oh))) & 0xffu) << 1;
    }
    if (lane < 4) {                   // zero margin slots 0,9,10,11
        int zs = (lane == 0) ? 0 : (8 + lane);
        spk[base + zs] = 0; npk[base + zs] = 0;
    }
}

// --- grouped 4x4 weights -> per-(oc,ic,kh) nibbles: sign | nz<<8 ---
template <int C>
__global__ void k_wpackg(const float* __restrict__ w, u32* __restrict__ wpk)
{
    int oc = blockIdx.x * blockDim.x + threadIdx.x;
    if (oc >= C) return;
    const float* p = w + oc * 32;
#pragma unroll
    for (int r = 0; r < 8; ++r) {           // r = ic*4 + kh
        u32 sn = 0, nz = 0;
#pragma unroll
        for (int kw = 0; kw < 4; ++kw) {
            float v = p[r * 4 + kw];
            sn |= (u32)(v > 0.f) << kw;
            nz |= (u32)(v != 0.f) << kw;
        }
        wpk[oc * 8 + r] = sn | (nz << 8);
    }
}

// --- grouped 4x4 binary conv, bit-packed in, int8 out. Thread=(b,group,row). ---
template <int C, int H>
__global__ __launch_bounds__(256) void k_convg_bp(const u32* __restrict__ spk,
                                                  const u32* __restrict__ npk,
                                                  const u32* __restrict__ wpk,
                                                  signed char* __restrict__ out)
{
    constexpr int SLOTS = (H == 16) ? 20 : 12;
    int t = blockIdx.x * 256 + threadIdx.x;
    int h = t % H; int r0 = t / H;
    int g = r0 % (C / 2); int b = r0 / (C / 2);
    const u32* sp = spk + (size_t)(b * C + 2 * g) * SLOTS + h;
    const u32* np = npk + (size_t)(b * C + 2 * g) * SLOTS + h;
    u32 S[8], N[8];
#pragma unroll
    for (int jc = 0; jc < 2; ++jc)
#pragma unroll
        for (int jj = 0; jj < 4; ++jj) {    // slot h+jj = input row h-1+jj
            S[jc * 4 + jj] = sp[jc * SLOTS + jj];
            N[jc * 4 + jj] = np[jc * SLOTS + jj];
        }
    const u32* wq = wpk + (size_t)(2 * g) * 8;
    u32 Ws0[8], Wn0[8], Ws1[8], Wn1[8];
#pragma unroll
    for (int r = 0; r < 8; ++r) {
        u32 a = wq[r];      Ws0[r] = a & 15u;  Wn0[r] = (a >> 8) & 15u;
        u32 bb = wq[8 + r]; Ws1[r] = bb & 15u; Wn1[r] = (bb >> 8) & 15u;
    }
    int v0[H], v1[H];
#pragma unroll
    for (int w = 0; w < H; ++w) {
        int snz0 = 0, smis0 = 0, snz1 = 0, smis1 = 0;
#pragma unroll
        for (int r = 0; r < 8; ++r) {
            u32 ss = (S[r] >> w) & 15u;
            u32 nn = (N[r] >> w) & 15u;
            u32 nz0 = nn & Wn0[r]; u32 m0 = (ss ^ Ws0[r]) & nz0;
            snz0 += __popc(nz0); smis0 += __popc(m0);
            u32 nz1 = nn & Wn1[r]; u32 m1 = (ss ^ Ws1[r]) & nz1;
            snz1 += __popc(nz1); smis1 += __popc(m1);
        }
        v0[w] = snz0 - 2 * smis0;
        v1[w] = snz1 - 2 * smis1;
    }
    signed char* o0 = out + ((size_t)((b * C + 2 * g) * H + h)) * H;
    signed char* o1 = o0 + (size_t)H * H;
    u32 wb0[H / 4], wb1[H / 4];
#pragma unroll
    for (int j = 0; j < H / 4; ++j) {
        wb0[j] = pack4(v0[4*j], v0[4*j+1], v0[4*j+2], v0[4*j+3]);
        wb1[j] = pack4(v1[4*j], v1[4*j+1], v1[4*j+2], v1[4*j+3]);
    }
    if constexpr (H == 16) {
        *(uint4*)o0 = make_uint4(wb0[0], wb0[1], wb0[2], wb0[3]);
        *(uint4*)o1 = make_uint4(wb1[0], wb1[1], wb1[2], wb1[3]);
    } else {
        *(uint2*)o0 = make_uint2(wb0[0], wb0[1]);
        *(uint2*)o1 = make_uint2(wb1[0], wb1[1]);
    }
}

// --- bn + binarize + channel-bitpack from int8: act[t] = {signs..., nz...} ---
template <int C, int HW>
__global__ __launch_bounds__(256) void k_bnpackC(const signed char* __restrict__ q,
                                                 const float4* __restrict__ st,
                                                 u32* __restrict__ act)
{
    constexpr int W = C / 32;
    int t = blockIdx.x * 256 + threadIdx.x;   // t = b*HW + hw
    int hw = t % HW; int b = t / HW;
    const signed char* qp = q + (size_t)b * C * HW + hw;
    u32* ap = act + (size_t)t * 2 * W;
#pragma unroll
    for (int j = 0; j < W; ++j) {
        u32 sv = 0, nv = 0;
#pragma unroll
        for (int k = 0; k < 32; ++k) {
            int c = j * 32 + k;
            float4 s = st[c];
            float v = ((float)qp[(size_t)c * HW] - s.x) * s.y + s.z;
            sv |= (u32)(v > 0.f) << k;
            nv |= (u32)(v != 0.f) << k;
        }
        ap[j] = sv; ap[W + j] = nv;
    }
}

// --- 1x1 weights -> packed words: [oc][0..W-1]=sign, [W..2W-1]=nz ---
template <int Cout, int Cin>
__global__ void k_wpack1x1(const float* __restrict__ w, u32* __restrict__ wp)
{
    constexpr int W = Cin / 32;
    int oc = blockIdx.x * blockDim.x + threadIdx.x;
    if (oc >= Cout) return;
    const float* p = w + (size_t)oc * Cin;
#pragma unroll
    for (int j = 0; j < W; ++j) {
        u32 sv = 0, nv = 0;
#pragma unroll
        for (int k = 0; k < 32; ++k) {
            float v = p[j * 32 + k];
            sv |= (u32)(v > 0.f) << k;
            nv |= (u32)(v != 0.f) << k;
        }
        wp[(size_t)oc * 2 * W + j] = sv;
        wp[(size_t)oc * 2 * W + W + j] = nv;
    }
}

// --- 1x1 conv, Cin=64, Cout=256, HW=256, int8 out. Thread=(b,hw). ---
__global__ __launch_bounds__(256) void k_conv1x1_bp2(const u32* __restrict__ act,
                                                     const u32* __restrict__ wp,
                                                     signed char* __restrict__ out)
{
    int t = blockIdx.x * 256 + threadIdx.x;   // t = b*256 + hw
    int hw = t & 255; int b = t >> 8;
    uint4 av = ((const uint4*)act)[t];        // s0,s1,n0,n1
    signed char* op = out + (size_t)b * 256 * 256 + hw;
#pragma unroll 8
    for (int oc = 0; oc < 256; ++oc) {
        uint4 wv = ((const uint4*)wp)[oc];    // wave-uniform -> scalar loads
        u32 nz0 = av.z & wv.z, nz1 = av.w & wv.w;
        u32 m0 = (av.x ^ wv.x) & nz0, m1 = (av.y ^ wv.y) & nz1;
        int dot = __popc(nz0) + __popc(nz1) - 2 * (__popc(m0) + __popc(m1));
        op[(size_t)oc << 8] = (signed char)dot;
    }
}

// --- 1x1 conv, Cin=256, Cout=256 (4 chunks), HW=64, int16 out. ---
__global__ __launch_bounds__(256) void k_conv1x1_bp3(const u32* __restrict__ act,
                                                     const u32* __restrict__ wp,
                                                     short* __restrict__ out)
{
    int t = blockIdx.x * 256 + threadIdx.x;
    int hw = t & 63; int ch = (t >> 6) & 3; int b = t >> 8;
    const u32* ap = act + (size_t)(b * 64 + hw) * 16;
    u32 as[8], an[8];
#pragma unroll
    for (int j = 0; j < 8; ++j) { as[j] = ap[j]; an[j] = ap[8 + j]; }
    short* op = out + (size_t)b * 256 * 64 + hw;
#pragma unroll 4
    for (int oc = ch * 64; oc < ch * 64 + 64; ++oc) {
        const u32* wq = wp + oc * 16;
        int snz = 0, smis = 0;
#pragma unroll
        for (int j = 0; j < 8; ++j) {
            u32 nz = an[j] & wq[8 + j];
            u32 m = (as[j] ^ wq[j]) & nz;
            snz += __popc(nz); smis += __popc(m);
        }
        op[(size_t)oc * 64] = (short)(snz - 2 * smis);
    }
}

// --- FC with bn3_2 fused, int16 features ---
__global__ __launch_bounds__(64) void k_fc(const short* __restrict__ f,
                                           const float4* __restrict__ st,
                                           const float* __restrict__ fcw,
                                           const float* __restrict__ fcb,
                                           float* __restrict__ out)
{
    int b = blockIdx.x, n = blockIdx.y;
    int lane = threadIdx.x;
    const short* fb = f + (size_t)b * 16384;
    const float* wn = fcw + (size_t)n * 16384;
    float acc = 0.f;
    for (int k = lane; k < 16384; k += 64) {
        int c = k >> 6;
        float4 s = st[c];
        float v = ((float)fb[k] - s.x) * s.y + s.z;
        acc += v * wn[k];
    }
    for (int off = 32; off > 0; off >>= 1) acc += __shfl_down(acc, off);
    if (lane == 0) out[b * 10 + n] = acc + fcb[n];
}

extern "C" void kernel_launch(void* const* d_in, const int* in_sizes, int n_in,
                              void* d_out, int out_size, void* d_ws, size_t ws_size,
                              hipStream_t stream)
{
    const float* x    = (const float*)d_in[0];
    const float* w1   = (const float*)d_in[1];
    const float* g1   = (const float*)d_in[2];
    const float* b1   = (const float*)d_in[3];
    const float* w2_1 = (const float*)d_in[4];
    const float* g2_1 = (const float*)d_in[5];
    const float* b2_1 = (const float*)d_in[6];
    const float* w2_2 = (const float*)d_in[7];
    const float* g2_2 = (const float*)d_in[8];
    const float* b2_2 = (const float*)d_in[9];
    const float* w3_1 = (const float*)d_in[10];
    const float* g3_1 = (const float*)d_in[11];
    const float* b3_1 = (const float*)d_in[12];
    const float* w3_2 = (const float*)d_in[13];
    const float* g3_2 = (const float*)d_in[14];
    const float* b3_2 = (const float*)d_in[15];
    const float* fcw  = (const float*)d_in[16];
    const float* fcb  = (const float*)d_in[17];
    float* out = (float*)d_out;

    // workspace layout (bytes)
    const size_t OFF_BIG   = 0;           // 134,217,728  conv1 f32 out; later conv2_2 int8 out
    const size_t OFF_F3    = 134217728;   // 16,777,216   conv3_2 int16 out
    const size_t OFF_Q     = 150994944;   // 8,388,608    convg int8 outs
    const size_t OFF_SPK2  = 159383552;   // 2,621,440
    const size_t OFF_NPK2  = 162004992;   // 2,621,440
    const size_t OFF_SPK3  = 164626432;   // 6,291,456
    const size_t OFF_NPK3  = 170917888;   // 6,291,456
    const size_t OFF_A     = 177209344;   // 2,097,152
    const size_t OFF_WPK21 = 179306496;   // 2,048
    const size_t OFF_WPK31 = 179308544;   // 8,192
    const size_t OFF_WP22  = 179316736;   // 4,096
    const size_t OFF_WP32  = 179320832;   // 16,384
    const size_t OFF_PART  = 179337216;   // 262,144
    const size_t OFF_ST    = 179599360;   // 24,576
    const size_t OFF_SW1   = 179623936;   // 12,288
    const size_t NEED      = OFF_SW1 + 12288;
    if (ws_size < NEED) return;

    char* ws = (char*)d_ws;
    float* big = (float*)(ws + OFF_BIG);
    signed char* big8 = (signed char*)(ws + OFF_BIG);
    short* f16 = (short*)(ws + OFF_F3);
    signed char* q8 = (signed char*)(ws + OFF_Q);
    u32* spk2  = (u32*)(ws + OFF_SPK2);
    u32* npk2  = (u32*)(ws + OFF_NPK2);
    u32* spk3  = (u32*)(ws + OFF_SPK3);
    u32* npk3  = (u32*)(ws + OFF_NPK3);
    u32* actA  = (u32*)(ws + OFF_A);
    u32* wpk21 = (u32*)(ws + OFF_WPK21);
    u32* wpk31 = (u32*)(ws + OFF_WPK31);
    u32* wp22  = (u32*)(ws + OFF_WP22);
    u32* wp32  = (u32*)(ws + OFF_WP32);
    double* part = (double*)(ws + OFF_PART);
    float4* st1  = (float4*)(ws + OFF_ST);
    float4* st21 = st1 + 256;
    float4* st22 = st21 + 256;
    float4* st31 = st22 + 256;
    float4* st32 = st31 + 256;
    float* sw1f  = (float*)(ws + OFF_SW1);

    // ---- layer 1 ----
    k_wsignf<<<12, 256, 0, stream>>>(w1, sw1f, 3072);
    k_conv1<<<2048, 256, 0, stream>>>(x, sw1f, big);                     // [512,64,32,32] f32
    k_statsf4<<<dim3(64, 64), 256, 0, stream>>>(big, part, 64, 1024, 8);
    k_finalize<<<1, 256, 0, stream>>>(part, 64, 512 * 1024, g1, b1, st1, 64);
    k_poolpack1<<<32768, 256, 0, stream>>>(big, st1, spk2, npk2);        // packed 16x16

    // ---- layer 2 ----
    k_wpackg<64><<<1, 64, 0, stream>>>(w2_1, wpk21);
    k_convg_bp<64, 16><<<1024, 256, 0, stream>>>(spk2, npk2, wpk21, q8); // [512,64,16,16] i8
    k_stats_i8<<<dim3(64, 64), 256, 0, stream>>>(q8, part, 64, 256, 8);
    k_finalize<<<1, 256, 0, stream>>>(part, 64, 512 * 256, g2_1, b2_1, st21, 64);
    k_bnpackC<64, 256><<<512, 256, 0, stream>>>(q8, st21, actA);
    k_wpack1x1<256, 64><<<1, 256, 0, stream>>>(w2_2, wp22);
    k_conv1x1_bp2<<<512, 256, 0, stream>>>(actA, wp22, big8);            // [512,256,16,16] i8
    k_stats_i8<<<dim3(256, 32), 256, 0, stream>>>(big8, part, 256, 256, 16);
    k_finalize<<<1, 256, 0, stream>>>(part, 32, 512 * 256, g2_2, b2_2, st22, 256);
    k_poolpack3<<<32768, 256, 0, stream>>>(big8, st22, spk3, npk3);      // packed 8x8

    // ---- layer 3 ----
    k_wpackg<256><<<1, 256, 0, stream>>>(w3_1, wpk31);
    k_convg_bp<256, 8><<<2048, 256, 0, stream>>>(spk3, npk3, wpk31, q8); // [512,256,8,8] i8
    k_stats_i8<<<dim3(256, 32), 256, 0, stream>>>(q8, part, 256, 64, 16);
    k_finalize<<<1, 256, 0, stream>>>(part, 32, 512 * 64, g3_1, b3_1, st31, 256);
    k_bnpackC<256, 64><<<128, 256, 0, stream>>>(q8, st31, actA);
    k_wpack1x1<256, 256><<<1, 256, 0, stream>>>(w3_2, wp32);
    k_conv1x1_bp3<<<512, 256, 0, stream>>>(actA, wp32, f16);             // [512,256,8,8] i16
    k_stats_i16<<<dim3(256, 32), 256, 0, stream>>>(f16, part, 256, 64, 16);
    k_finalize<<<1, 256, 0, stream>>>(part, 32, 512 * 64, g3_2, b3_2, st32, 256);

    // ---- FC (bn3_2 fused) ----
    k_fc<<<dim3(512, 10), 64, 0, stream>>>(f16, st32, fcw, fcb, out);
}